// Round 1
// baseline (541.161 us; speedup 1.0000x reference)
//
#include <hip/hip_runtime.h>
#include <hip/hip_bf16.h>

#define B_  2
#define S_  2048
#define D_  1024
#define H_  16
#define HD_ 64
#define M_  (B_*S_)   // 4096 rows of x

typedef __attribute__((ext_vector_type(8))) short short8;
typedef __attribute__((ext_vector_type(4))) float f32x4;

#define MFMA16(a, b, c) __builtin_amdgcn_mfma_f32_16x16x32_bf16((a), (b), (c), 0, 0, 0)

static __device__ inline short f2bf(float f) {
    union { float f; unsigned u; } v; v.f = f;
    unsigned r = v.u + 0x7FFFu + ((v.u >> 16) & 1u);   // round-to-nearest-even
    return (short)(r >> 16);
}

// ---------------- x (fp32) -> bf16, vectorized ----------------
__global__ void cvt_x_kernel(const float* __restrict__ x, short* __restrict__ xb, int n4) {
    int i = blockIdx.x * blockDim.x + threadIdx.x;
    int stride = gridDim.x * blockDim.x;
    for (; i < n4; i += stride) {
        float4 v = ((const float4*)x)[i];
        short4 o;
        o.x = f2bf(v.x); o.y = f2bf(v.y); o.z = f2bf(v.z); o.w = f2bf(v.w);
        ((short4*)xb)[i] = o;
    }
}

// ---------------- W [K][N] fp32 -> Wt [N][K] bf16 ----------------
__global__ void transpose_w_kernel(const float* __restrict__ W, short* __restrict__ Wt) {
    __shared__ float tile[32][33];
    int tx = threadIdx.x & 31, ty = threadIdx.x >> 5;   // 32x8
    int n0 = blockIdx.x * 32, k0 = blockIdx.y * 32;
#pragma unroll
    for (int i = 0; i < 4; ++i)
        tile[ty + 8 * i][tx] = W[(size_t)(k0 + ty + 8 * i) * D_ + n0 + tx];
    __syncthreads();
#pragma unroll
    for (int i = 0; i < 4; ++i)
        Wt[(size_t)(n0 + ty + 8 * i) * D_ + k0 + tx] = f2bf(tile[tx][ty + 8 * i]);
}

// ---------------- GEMM: C[M][N] = A[M][K] * Bt[N][K]^T ----------------
// MODE 0: write bf16 into [B][H][S][HD]          (Q, K)
// MODE 1: write bf16 into [B][H][HD][S]          (V transposed)
// MODE 2: write fp32 row-major [M][N] + bias[n]  (final output)
template <int MODE>
__global__ __launch_bounds__(256) void gemm_kernel(const short* __restrict__ A,
                                                   const short* __restrict__ Bt,
                                                   const float* __restrict__ bias,
                                                   void* __restrict__ out) {
    const int K = D_;
    const int nb = D_ / 64;                 // 16 N-blocks
    int bm = blockIdx.x / nb, bn = blockIdx.x % nb;
    int tid = threadIdx.x, w = tid >> 6, l = tid & 63;
    int lhi = l >> 4, llo = l & 15;
    int mrow = bm * 64 + w * 16;            // wave's 16 rows
    int ncol = bn * 64;                     // wave's 64 cols

    f32x4 acc[4];
#pragma unroll
    for (int n = 0; n < 4; ++n) acc[n] = (f32x4){0.f, 0.f, 0.f, 0.f};

    const short* Ap = A + (size_t)(mrow + llo) * K + 8 * lhi;
    const short* Bp = Bt + (size_t)(ncol + llo) * K + 8 * lhi;

#pragma unroll 2
    for (int kk = 0; kk < K; kk += 32) {
        short8 af = *(const short8*)(Ap + kk);
#pragma unroll
        for (int n = 0; n < 4; ++n) {
            short8 bf = *(const short8*)(Bp + (size_t)n * 16 * K + kk);
            acc[n] = MFMA16(af, bf, acc[n]);
        }
    }

#pragma unroll
    for (int n = 0; n < 4; ++n) {
        int col = ncol + n * 16 + llo;
#pragma unroll
        for (int j = 0; j < 4; ++j) {
            int row = mrow + lhi * 4 + j;
            float v = acc[n][j];
            if (MODE == 2) {
                ((float*)out)[(size_t)row * D_ + col] = v + bias[col];
            } else {
                int b = row >> 11, s = row & (S_ - 1);
                int h = col >> 6, hd = col & 63;
                short* o = (short*)out;
                if (MODE == 0)
                    o[((size_t)(b * H_ + h) * S_ + s) * HD_ + hd] = f2bf(v);
                else
                    o[((size_t)(b * H_ + h) * HD_ + hd) * S_ + s] = f2bf(v);
            }
        }
    }
}

// ---------------- causal flash attention ----------------
// Q,K: [B][H][S][HD] bf16, Vt: [B][H][HD][S] bf16 -> ctx [B][S][D] bf16
__global__ __launch_bounds__(256) void attn_kernel(const short* __restrict__ Q,
                                                   const short* __restrict__ Kg,
                                                   const short* __restrict__ Vt,
                                                   short* __restrict__ ctx) {
    __shared__ __align__(16) char plds[4][1024];   // per-wave 16x32 bf16 P tile, swizzled
    const int QT = S_ / 64;                        // 32 q-tiles per head
    int bh = blockIdx.x / QT, qt = blockIdx.x % QT;
    int tid = threadIdx.x, w = tid >> 6, l = tid & 63;
    int lhi = l >> 4, llo = l & 15;
    int qbase = qt * 64 + w * 16;                  // wave's first q row

    const short* Qh = Q + (size_t)bh * S_ * HD_;
    const short* Kh = Kg + (size_t)bh * S_ * HD_;
    const short* Vh = Vt + (size_t)bh * HD_ * S_;
    char* pb = plds[w];

    // Q fragments (hoisted): rows qbase..qbase+15, d in [0,64)
    short8 aq0 = *(const short8*)(Qh + (size_t)(qbase + llo) * HD_ + 8 * lhi);
    short8 aq1 = *(const short8*)(Qh + (size_t)(qbase + llo) * HD_ + 32 + 8 * lhi);

    f32x4 O[4];
#pragma unroll
    for (int n = 0; n < 4; ++n) O[n] = (f32x4){0.f, 0.f, 0.f, 0.f};
    float mrun[4] = {-1e30f, -1e30f, -1e30f, -1e30f};
    float lrun[4] = {0.f, 0.f, 0.f, 0.f};

    int nkt = (qbase + 47) >> 5;                   // k-tiles of 32 needed (causal)
    for (int kt = 0; kt < nkt; ++kt) {
        int c0 = kt * 32;
        f32x4 sc0 = (f32x4){0.f, 0.f, 0.f, 0.f};
        f32x4 sc1 = (f32x4){0.f, 0.f, 0.f, 0.f};
        {
            const short* Kb0 = Kh + (size_t)(c0 + llo) * HD_ + 8 * lhi;
            const short* Kb1 = Kh + (size_t)(c0 + 16 + llo) * HD_ + 8 * lhi;
            short8 b00 = *(const short8*)(Kb0);
            short8 b01 = *(const short8*)(Kb0 + 32);
            short8 b10 = *(const short8*)(Kb1);
            short8 b11 = *(const short8*)(Kb1 + 32);
            sc0 = MFMA16(aq0, b00, sc0);
            sc0 = MFMA16(aq1, b01, sc0);
            sc1 = MFMA16(aq0, b10, sc1);
            sc1 = MFMA16(aq1, b11, sc1);
        }
        bool full = (c0 + 31) <= qbase;            // no masking needed in this tile
#pragma unroll
        for (int j = 0; j < 4; ++j) {
            int qr = qbase + lhi * 4 + j;
            float v0 = sc0[j] * 0.125f;
            float v1 = sc1[j] * 0.125f;
            if (!full) {
                if (c0 + llo > qr)      v0 = -1e30f;
                if (c0 + 16 + llo > qr) v1 = -1e30f;
            }
            float mx = fmaxf(v0, v1);
            mx = fmaxf(mx, __shfl_xor(mx, 1));
            mx = fmaxf(mx, __shfl_xor(mx, 2));
            mx = fmaxf(mx, __shfl_xor(mx, 4));
            mx = fmaxf(mx, __shfl_xor(mx, 8));
            float mn = fmaxf(mrun[j], mx);
            float p0 = __expf(v0 - mn);
            float p1 = __expf(v1 - mn);
            float rs = p0 + p1;
            rs += __shfl_xor(rs, 1);
            rs += __shfl_xor(rs, 2);
            rs += __shfl_xor(rs, 4);
            rs += __shfl_xor(rs, 8);
            float alpha = __expf(mrun[j] - mn);
            lrun[j] = lrun[j] * alpha + rs;
            mrun[j] = mn;
            O[0][j] *= alpha; O[1][j] *= alpha; O[2][j] *= alpha; O[3][j] *= alpha;
            // write P row r (bf16) to swizzled LDS
            int r = lhi * 4 + j;
            int rb = r * 64, sw = (r & 3) << 4;
            *(short*)(pb + rb + ((llo * 2) ^ sw))        = f2bf(p0);
            *(short*)(pb + rb + (((16 + llo) * 2) ^ sw)) = f2bf(p1);
        }
        // read P as MFMA A-fragment: row=llo, k = 8*lhi..+8
        short8 pa = *(const short8*)(pb + llo * 64 + ((16 * lhi) ^ ((llo & 3) << 4)));
#pragma unroll
        for (int n = 0; n < 4; ++n) {
            short8 bv = *(const short8*)(Vh + (size_t)(n * 16 + llo) * S_ + c0 + 8 * lhi);
            O[n] = MFMA16(pa, bv, O[n]);
        }
    }

    int b = bh >> 4, h = bh & 15;
#pragma unroll
    for (int j = 0; j < 4; ++j) {
        float inv = 1.0f / lrun[j];
        int row = qbase + lhi * 4 + j;
        size_t base = ((size_t)(b * S_ + row)) * D_ + h * HD_;
#pragma unroll
        for (int n = 0; n < 4; ++n)
            ctx[base + n * 16 + llo] = f2bf(O[n][j] * inv);
    }
}

extern "C" void kernel_launch(void* const* d_in, const int* in_sizes, int n_in,
                              void* d_out, int out_size, void* d_ws, size_t ws_size,
                              hipStream_t stream) {
    const float* x  = (const float*)d_in[0];
    const float* Wq = (const float*)d_in[1];
    const float* Wk = (const float*)d_in[2];
    const float* Wv = (const float*)d_in[3];
    const float* Wo = (const float*)d_in[4];
    const float* bo = (const float*)d_in[5];
    float* out = (float*)d_out;

    char* ws = (char*)d_ws;
    short* xb  = (short*)(ws);                       // 8 MB (reused as ctx later)
    short* Wqt = (short*)(ws + (size_t)(8 << 20));   // 2 MB each
    short* Wkt = Wqt + (1 << 20);
    short* Wvt = Wkt + (1 << 20);
    short* Wot = Wvt + (1 << 20);
    short* Qb  = (short*)(ws + (size_t)(16 << 20));  // 8 MB each
    short* Kb  = Qb + (size_t)M_ * D_;
    short* Vtb = Kb + (size_t)M_ * D_;
    short* ctx = xb;                                 // alias: xb dead after QKV GEMMs

    cvt_x_kernel<<<2048, 256, 0, stream>>>(x, xb, M_ * D_ / 4);
    dim3 tg(32, 32);
    transpose_w_kernel<<<tg, 256, 0, stream>>>(Wq, Wqt);
    transpose_w_kernel<<<tg, 256, 0, stream>>>(Wk, Wkt);
    transpose_w_kernel<<<tg, 256, 0, stream>>>(Wv, Wvt);
    transpose_w_kernel<<<tg, 256, 0, stream>>>(Wo, Wot);

    int gblocks = (M_ / 64) * (D_ / 64);             // 1024
    gemm_kernel<0><<<gblocks, 256, 0, stream>>>(xb, Wqt, nullptr, Qb);
    gemm_kernel<0><<<gblocks, 256, 0, stream>>>(xb, Wkt, nullptr, Kb);
    gemm_kernel<1><<<gblocks, 256, 0, stream>>>(xb, Wvt, nullptr, Vtb);

    attn_kernel<<<B_ * H_ * (S_ / 64), 256, 0, stream>>>(Qb, Kb, Vtb, ctx);

    gemm_kernel<2><<<gblocks, 256, 0, stream>>>(ctx, Wot, bo, out);
}

// Round 2
// 236.327 us; speedup vs baseline: 2.2899x; 2.2899x over previous
//
#include <hip/hip_runtime.h>
#include <hip/hip_bf16.h>

#define B_  2
#define S_  2048
#define D_  1024
#define H_  16
#define HD_ 64
#define M_  (B_*S_)   // 4096 rows of x

typedef __attribute__((ext_vector_type(8))) short short8;
typedef __attribute__((ext_vector_type(4))) float f32x4;

#define MFMA16(a, b, c) __builtin_amdgcn_mfma_f32_16x16x32_bf16((a), (b), (c), 0, 0, 0)

static __device__ inline short f2bf(float f) {
    union { float f; unsigned u; } v; v.f = f;
    unsigned r = v.u + 0x7FFFu + ((v.u >> 16) & 1u);   // round-to-nearest-even
    return (short)(r >> 16);
}

static __device__ __forceinline__ void gl_lds16(const short* g, short* l) {
    __builtin_amdgcn_global_load_lds(
        (const __attribute__((address_space(1))) void*)g,
        (__attribute__((address_space(3))) void*)l, 16, 0, 0);
}

// ---------------- x (fp32) -> bf16, vectorized ----------------
__global__ void cvt_x_kernel(const float* __restrict__ x, short* __restrict__ xb, int n4) {
    int i = blockIdx.x * blockDim.x + threadIdx.x;
    int stride = gridDim.x * blockDim.x;
    for (; i < n4; i += stride) {
        float4 v = ((const float4*)x)[i];
        short4 o;
        o.x = f2bf(v.x); o.y = f2bf(v.y); o.z = f2bf(v.z); o.w = f2bf(v.w);
        ((short4*)xb)[i] = o;
    }
}

// ---------------- W [K][N] fp32 -> Wt [N][K] bf16 ----------------
__global__ void transpose_w_kernel(const float* __restrict__ W, short* __restrict__ Wt) {
    __shared__ float tile[32][33];
    int tx = threadIdx.x & 31, ty = threadIdx.x >> 5;   // 32x8
    int n0 = blockIdx.x * 32, k0 = blockIdx.y * 32;
#pragma unroll
    for (int i = 0; i < 4; ++i)
        tile[ty + 8 * i][tx] = W[(size_t)(k0 + ty + 8 * i) * D_ + n0 + tx];
    __syncthreads();
#pragma unroll
    for (int i = 0; i < 4; ++i)
        Wt[(size_t)(n0 + ty + 8 * i) * D_ + k0 + tx] = f2bf(tile[tx][ty + 8 * i]);
}

// ---------------- m97-style 128x128 GEMM: C = A[M][1024] * Bt[N][1024]^T ----
// MODE 0: fused QKV epilogue. out = base of Q; K at +M_*D_, V^T at +2*M_*D_.
//         col in [0,3072): proj=col>>10. Q,K: [b][h][s][hd]; V: [b][h][hd][s].
// MODE 2: fp32 row-major [M][1024] + bias.
template <int MODE>
__global__ __launch_bounds__(256) void gemm128(const short* __restrict__ A,
                                               const short* __restrict__ Bt,
                                               const float* __restrict__ bias,
                                               void* __restrict__ out, int NB) {
    __shared__ __align__(16) short Asm[128 * 32];
    __shared__ __align__(16) short Bsm[128 * 32];
    int bm = blockIdx.x / NB, bn = blockIdx.x % NB;
    int tid = threadIdx.x, l = tid & 63, w = tid >> 6;
    int lhi = l >> 4, llo = l & 15;
    int wm = w >> 1, wn = w & 1;

    f32x4 acc[4][4];
#pragma unroll
    for (int m = 0; m < 4; ++m)
#pragma unroll
        for (int n = 0; n < 4; ++n) acc[m][n] = (f32x4){0.f, 0.f, 0.f, 0.f};

    const short* Ag = A + (size_t)(bm * 128) * 1024;
    const short* Bg = Bt + (size_t)(bn * 128) * 1024;
    int c0 = tid, c1 = 256 + tid;
    int r0 = c0 >> 2, k_0 = (c0 & 3) * 8;
    int r1 = c1 >> 2, k_1 = (c1 & 3) * 8;

    for (int k0 = 0; k0 < 1024; k0 += 32) {
        gl_lds16(Ag + (size_t)r0 * 1024 + k0 + k_0, &Asm[c0 * 8]);
        gl_lds16(Ag + (size_t)r1 * 1024 + k0 + k_1, &Asm[c1 * 8]);
        gl_lds16(Bg + (size_t)r0 * 1024 + k0 + k_0, &Bsm[c0 * 8]);
        gl_lds16(Bg + (size_t)r1 * 1024 + k0 + k_1, &Bsm[c1 * 8]);
        __syncthreads();
        short8 af[4], bf[4];
#pragma unroll
        for (int m = 0; m < 4; ++m)
            af[m] = *(const short8*)&Asm[(wm * 64 + m * 16 + llo) * 32 + lhi * 8];
#pragma unroll
        for (int n = 0; n < 4; ++n)
            bf[n] = *(const short8*)&Bsm[(wn * 64 + n * 16 + llo) * 32 + lhi * 8];
#pragma unroll
        for (int m = 0; m < 4; ++m)
#pragma unroll
            for (int n = 0; n < 4; ++n)
                acc[m][n] = MFMA16(af[m], bf[n], acc[m][n]);
        __syncthreads();
    }

    int rowb = bm * 128 + wm * 64, colb = bn * 128 + wn * 64;
#pragma unroll
    for (int m = 0; m < 4; ++m) {
#pragma unroll
        for (int n = 0; n < 4; ++n) {
            int col = colb + n * 16 + llo;
#pragma unroll
            for (int j = 0; j < 4; ++j) {
                int row = rowb + m * 16 + lhi * 4 + j;
                float v = acc[m][n][j];
                if (MODE == 2) {
                    ((float*)out)[(size_t)row * 1024 + col] = v + bias[col];
                } else {
                    int proj = col >> 10, n1 = col & 1023;
                    int h = n1 >> 6, hd = n1 & 63;
                    int b = row >> 11, s = row & 2047;
                    short* o = (short*)out;
                    size_t off;
                    if (proj == 0)
                        off = ((size_t)(b * 16 + h) * 2048 + s) * 64 + hd;
                    else if (proj == 1)
                        off = (size_t)M_ * D_ + ((size_t)(b * 16 + h) * 2048 + s) * 64 + hd;
                    else
                        off = (size_t)2 * M_ * D_ + ((size_t)(b * 16 + h) * 64 + hd) * 2048 + s;
                    o[off] = f2bf(v);
                }
            }
        }
    }
}

// ---------------- causal flash attention, balanced pairing ----------------
// 512 threads = 8 waves. Waves 0-3: q-tile `pair`; waves 4-7: q-tile `31-pair`.
// Every SIMD gets (pair+1)+(32-pair)=33 k-tile units -> perfect static balance.
__global__ __launch_bounds__(512, 4) void attn_kernel(const short* __restrict__ Q,
                                                      const short* __restrict__ Kg,
                                                      const short* __restrict__ Vt,
                                                      short* __restrict__ ctx) {
    __shared__ __align__(16) char plds[8][2048];   // per-wave 16x64 bf16 P tile, swizzled
    int tid = threadIdx.x, w = tid >> 6, l = tid & 63;
    int lhi = l >> 4, llo = l & 15;
    int bh = blockIdx.x & 31;
    int pair = blockIdx.x >> 5;                    // 0..15
    int qt = (w < 4) ? pair : (31 - pair);
    int qbase = qt * 64 + (w & 3) * 16;            // wave's 16 q rows
    char* pb = plds[w];

    const short* Qh = Q + (size_t)bh * S_ * HD_;
    const short* Kh = Kg + (size_t)bh * S_ * HD_;
    const short* Vh = Vt + (size_t)bh * HD_ * S_;

    short8 aq0 = *(const short8*)(Qh + (size_t)(qbase + llo) * HD_ + 8 * lhi);
    short8 aq1 = *(const short8*)(Qh + (size_t)(qbase + llo) * HD_ + 32 + 8 * lhi);

    f32x4 O[4];
#pragma unroll
    for (int n = 0; n < 4; ++n) O[n] = (f32x4){0.f, 0.f, 0.f, 0.f};
    float mrun[4] = {-1e30f, -1e30f, -1e30f, -1e30f};
    float lpart[4] = {0.f, 0.f, 0.f, 0.f};        // per-lane partial sums (deferred reduce)

    int nkt = qt + 1;                              // 64-wide k-tiles (causal)
    for (int kt = 0; kt < nkt; ++kt) {
        int c0 = kt * 64;
        f32x4 sc[4];
#pragma unroll
        for (int cb = 0; cb < 4; ++cb) {
            const short* Kb = Kh + (size_t)(c0 + cb * 16 + llo) * HD_ + 8 * lhi;
            short8 kf0 = *(const short8*)(Kb);
            short8 kf1 = *(const short8*)(Kb + 32);
            f32x4 z = (f32x4){0.f, 0.f, 0.f, 0.f};
            z = MFMA16(aq0, kf0, z);
            z = MFMA16(aq1, kf1, z);
            sc[cb] = z;
        }
        bool full = (c0 + 63) <= qbase;
#pragma unroll
        for (int j = 0; j < 4; ++j) {
            int qr = qbase + lhi * 4 + j;
            float v0 = sc[0][j] * 0.125f;
            float v1 = sc[1][j] * 0.125f;
            float v2 = sc[2][j] * 0.125f;
            float v3 = sc[3][j] * 0.125f;
            if (!full) {
                if (c0 + llo > qr)      v0 = -1e30f;
                if (c0 + 16 + llo > qr) v1 = -1e30f;
                if (c0 + 32 + llo > qr) v2 = -1e30f;
                if (c0 + 48 + llo > qr) v3 = -1e30f;
            }
            float mx = fmaxf(fmaxf(v0, v1), fmaxf(v2, v3));
            mx = fmaxf(mx, __shfl_xor(mx, 1));
            mx = fmaxf(mx, __shfl_xor(mx, 2));
            mx = fmaxf(mx, __shfl_xor(mx, 4));
            mx = fmaxf(mx, __shfl_xor(mx, 8));
            float mn = fmaxf(mrun[j], mx);
            float alpha = __expf(mrun[j] - mn);
            mrun[j] = mn;
            float p0 = __expf(v0 - mn), p1 = __expf(v1 - mn);
            float p2 = __expf(v2 - mn), p3 = __expf(v3 - mn);
            lpart[j] = lpart[j] * alpha + (p0 + p1) + (p2 + p3);
            O[0][j] *= alpha; O[1][j] *= alpha; O[2][j] *= alpha; O[3][j] *= alpha;
            int r = lhi * 4 + j;
            char* rb = pb + r * 128;
            int sw = (r & 7) << 4;
            *(short*)(rb + ((2 * llo) ^ sw))      = f2bf(p0);
            *(short*)(rb + ((2 * llo + 32) ^ sw)) = f2bf(p1);
            *(short*)(rb + ((2 * llo + 64) ^ sw)) = f2bf(p2);
            *(short*)(rb + ((2 * llo + 96) ^ sw)) = f2bf(p3);
        }
        int swr = (llo & 7) << 4;
        short8 pa0 = *(const short8*)(pb + llo * 128 + ((16 * lhi) ^ swr));
        short8 pa1 = *(const short8*)(pb + llo * 128 + ((64 + 16 * lhi) ^ swr));
#pragma unroll
        for (int n = 0; n < 4; ++n) {
            const short* Vb = Vh + (size_t)(n * 16 + llo) * S_ + c0 + 8 * lhi;
            short8 vf0 = *(const short8*)(Vb);
            short8 vf1 = *(const short8*)(Vb + 32);
            O[n] = MFMA16(pa0, vf0, O[n]);
            O[n] = MFMA16(pa1, vf1, O[n]);
        }
    }

    int b = bh >> 4, h = bh & 15;
#pragma unroll
    for (int j = 0; j < 4; ++j) {
        float ls = lpart[j];
        ls += __shfl_xor(ls, 1);
        ls += __shfl_xor(ls, 2);
        ls += __shfl_xor(ls, 4);
        ls += __shfl_xor(ls, 8);
        float inv = 1.0f / ls;
        int row = qbase + lhi * 4 + j;
        size_t base = ((size_t)(b * S_ + row)) * D_ + h * HD_;
#pragma unroll
        for (int n = 0; n < 4; ++n)
            ctx[base + n * 16 + llo] = f2bf(O[n][j] * inv);
    }
}

extern "C" void kernel_launch(void* const* d_in, const int* in_sizes, int n_in,
                              void* d_out, int out_size, void* d_ws, size_t ws_size,
                              hipStream_t stream) {
    const float* x  = (const float*)d_in[0];
    const float* Wq = (const float*)d_in[1];
    const float* Wk = (const float*)d_in[2];
    const float* Wv = (const float*)d_in[3];
    const float* Wo = (const float*)d_in[4];
    const float* bo = (const float*)d_in[5];
    float* out = (float*)d_out;

    char* ws = (char*)d_ws;
    short* xb    = (short*)(ws);                       // 8 MB (reused as ctx later)
    short* Wqkvt = (short*)(ws + (size_t)(8 << 20));   // 6 MB: [3072][1024] bf16
    short* Wot   = (short*)(ws + (size_t)(14 << 20));  // 2 MB
    short* Qb    = (short*)(ws + (size_t)(16 << 20));  // 8 MB each
    short* Kb    = Qb + (size_t)M_ * D_;
    short* Vtb   = Qb + (size_t)2 * M_ * D_;
    short* ctx   = xb;                                 // alias: xb dead after QKV GEMM

    cvt_x_kernel<<<2048, 256, 0, stream>>>(x, xb, M_ * D_ / 4);
    dim3 tg(32, 32);
    transpose_w_kernel<<<tg, 256, 0, stream>>>(Wq, Wqkvt);
    transpose_w_kernel<<<tg, 256, 0, stream>>>(Wk, Wqkvt + (1 << 20));
    transpose_w_kernel<<<tg, 256, 0, stream>>>(Wv, Wqkvt + (2 << 20));
    transpose_w_kernel<<<tg, 256, 0, stream>>>(Wo, Wot);

    gemm128<0><<<32 * 24, 256, 0, stream>>>(xb, Wqkvt, nullptr, Qb, 24);   // fused QKV
    attn_kernel<<<512, 512, 0, stream>>>(Qb, Kb, Vtb, ctx);
    gemm128<2><<<32 * 8, 256, 0, stream>>>(ctx, Wot, bo, out, 8);          // out-proj
}